// Round 6
// baseline (362.679 us; speedup 1.0000x reference)
//
#include <hip/hip_runtime.h>
#include <hip/hip_bf16.h>

#define B_ 4
#define T_ 2048
#define C_ 1024
#define H_ 16
#define D_ 64
#define M_ (B_ * T_)   // 8192
#define N3_ (3 * C_)   // 3072

typedef __attribute__((ext_vector_type(4))) float f32x4;
typedef __attribute__((ext_vector_type(16))) float f32x16;
typedef __attribute__((ext_vector_type(8))) short bf16x8;

__device__ __forceinline__ ushort f2bf(float f) {
  union { float f; unsigned u; } v; v.f = f;
  unsigned r = v.u + 0x7fffu + ((v.u >> 16) & 1u);
  return (ushort)(r >> 16);
}

__device__ __forceinline__ void gload_lds16(const ushort* g, ushort* l) {
  __builtin_amdgcn_global_load_lds((const __attribute__((address_space(1))) void*)g,
                                   (__attribute__((address_space(3))) void*)l, 16, 0, 0);
}

__device__ __forceinline__ unsigned cvtpk_bf16(float lo, float hi) {
  unsigned r;
  asm("v_cvt_pk_bf16_f32 %0, %1, %2" : "=v"(r) : "v"(lo), "v"(hi));
  return r;
}

// ---------------- cast f32 -> bf16 (vectorized) ----------------
__global__ void cvt_bf16_kernel(const float* __restrict__ in, ushort* __restrict__ out, int n4) {
  int i = blockIdx.x * blockDim.x + threadIdx.x;
  int stride = gridDim.x * blockDim.x;
  for (; i < n4; i += stride) {
    float4 v = reinterpret_cast<const float4*>(in)[i];
    ushort4 o;
    o.x = f2bf(v.x); o.y = f2bf(v.y); o.z = f2bf(v.z); o.w = f2bf(v.w);
    reinterpret_cast<ushort4*>(out)[i] = o;
  }
}

// ------------- transpose + cast: in[K][N] f32 -> out[N][K] bf16 -------------
__global__ __launch_bounds__(256) void transpose_cvt_kernel(const float* __restrict__ in,
                                                            ushort* __restrict__ out,
                                                            int K, int N) {
  __shared__ float tile[64][65];
  int k0 = blockIdx.y * 64, n0 = blockIdx.x * 64;
  int t = threadIdx.x;
  int rr = t >> 6, cc = t & 63;
#pragma unroll
  for (int i = 0; i < 16; ++i) {
    int r = i * 4 + rr;
    tile[r][cc] = in[(size_t)(k0 + r) * N + n0 + cc];
  }
  __syncthreads();
#pragma unroll
  for (int i = 0; i < 16; ++i) {
    int r = i * 4 + rr;
    out[(size_t)(n0 + r) * K + k0 + cc] = f2bf(tile[cc][r]);
  }
}

// ---------------- QKV GEMM (m97 structure): qkv = x @ w_qkv + b -> q/k/vT ----------------
// q gets pre-scaled by 1/sqrt(D) = 0.125 here (folded softmax scale).
__global__ __launch_bounds__(256) void gemm_qkv_kernel(const ushort* __restrict__ A,
                                                       const ushort* __restrict__ Bt,
                                                       const float* __restrict__ bias,
                                                       ushort* __restrict__ qb,
                                                       ushort* __restrict__ kb,
                                                       ushort* __restrict__ vT) {
  __shared__ __align__(16) ushort As[128 * 32];
  __shared__ __align__(16) ushort Bs[128 * 32];
  const int tid = threadIdx.x;
  const int wid = tid >> 6, lane = tid & 63;
  const int wm = wid >> 1, wn = wid & 1;
  const int lr = lane & 15, lg = lane >> 4;
  const int bm = blockIdx.y * 128, bn = blockIdx.x * 128;
  const int srow = wid * 32 + (lane >> 2);
  const int scol = (lane & 3) * 8;
  ushort* lA = &As[wid * 32 * 32];
  ushort* lB = &Bs[wid * 32 * 32];
  const ushort* gA0 = A  + (size_t)(bm + srow) * 1024 + scol;
  const ushort* gB0 = Bt + (size_t)(bn + srow) * 1024 + scol;
  f32x4 acc[4][4] = {};
  for (int k0 = 0; k0 < 1024; k0 += 32) {
    gload_lds16(gA0 + k0, lA);
    gload_lds16(gA0 + k0 + 16 * 1024, lA + 16 * 32);
    gload_lds16(gB0 + k0, lB);
    gload_lds16(gB0 + k0 + 16 * 1024, lB + 16 * 32);
    __syncthreads();
    bf16x8 af[4], bfr[4];
#pragma unroll
    for (int f = 0; f < 4; ++f) {
      af[f]  = *(const bf16x8*)&As[(wm * 64 + f * 16 + lr) * 32 + lg * 8];
      bfr[f] = *(const bf16x8*)&Bs[(wn * 64 + f * 16 + lr) * 32 + lg * 8];
    }
#pragma unroll
    for (int fm = 0; fm < 4; ++fm)
#pragma unroll
      for (int fn = 0; fn < 4; ++fn)
        acc[fm][fn] = __builtin_amdgcn_mfma_f32_16x16x32_bf16(af[fm], bfr[fn], acc[fm][fn], 0, 0, 0);
    __syncthreads();
  }
#pragma unroll
  for (int fm = 0; fm < 4; ++fm)
#pragma unroll
    for (int fn = 0; fn < 4; ++fn) {
      int m0 = bm + wm * 64 + fm * 16 + lg * 4;
      int n  = bn + wn * 64 + fn * 16 + lr;
      float b = bias[n];
      int part = n >> 10, cch = n & 1023;
      int h = cch >> 6, d = cch & 63;
      int bb = m0 >> 11, t = m0 & 2047;
      size_t bh = (size_t)bb * H_ + h;
      if (part == 2) {
        ushort4 pv;
        pv.x = f2bf(acc[fm][fn][0] + b);
        pv.y = f2bf(acc[fm][fn][1] + b);
        pv.z = f2bf(acc[fm][fn][2] + b);
        pv.w = f2bf(acc[fm][fn][3] + b);
        *(ushort4*)&vT[(bh * D_ + d) * T_ + t] = pv;
      } else if (part == 0) {
#pragma unroll
        for (int r = 0; r < 4; ++r)
          qb[(bh * T_ + t + r) * D_ + d] = f2bf((acc[fm][fn][r] + b) * 0.125f);
      } else {
#pragma unroll
        for (int r = 0; r < 4; ++r)
          kb[(bh * T_ + t + r) * D_ + d] = f2bf(acc[fm][fn][r] + b);
      }
    }
}

// ---------------- Proj GEMM (m97 structure): out = y @ w_proj + b (f32 out) ----------------
__global__ __launch_bounds__(256) void gemm_proj_kernel(const ushort* __restrict__ A,
                                                        const ushort* __restrict__ Bt,
                                                        const float* __restrict__ bias,
                                                        float* __restrict__ out) {
  __shared__ __align__(16) ushort As[128 * 32];
  __shared__ __align__(16) ushort Bs[128 * 32];
  const int tid = threadIdx.x;
  const int wid = tid >> 6, lane = tid & 63;
  const int wm = wid >> 1, wn = wid & 1;
  const int lr = lane & 15, lg = lane >> 4;
  const int bm = blockIdx.y * 128, bn = blockIdx.x * 128;
  const int srow = wid * 32 + (lane >> 2);
  const int scol = (lane & 3) * 8;
  ushort* lA = &As[wid * 32 * 32];
  ushort* lB = &Bs[wid * 32 * 32];
  const ushort* gA0 = A  + (size_t)(bm + srow) * 1024 + scol;
  const ushort* gB0 = Bt + (size_t)(bn + srow) * 1024 + scol;
  f32x4 acc[4][4] = {};
  for (int k0 = 0; k0 < 1024; k0 += 32) {
    gload_lds16(gA0 + k0, lA);
    gload_lds16(gA0 + k0 + 16 * 1024, lA + 16 * 32);
    gload_lds16(gB0 + k0, lB);
    gload_lds16(gB0 + k0 + 16 * 1024, lB + 16 * 32);
    __syncthreads();
    bf16x8 af[4], bfr[4];
#pragma unroll
    for (int f = 0; f < 4; ++f) {
      af[f]  = *(const bf16x8*)&As[(wm * 64 + f * 16 + lr) * 32 + lg * 8];
      bfr[f] = *(const bf16x8*)&Bs[(wn * 64 + f * 16 + lr) * 32 + lg * 8];
    }
#pragma unroll
    for (int fm = 0; fm < 4; ++fm)
#pragma unroll
      for (int fn = 0; fn < 4; ++fn)
        acc[fm][fn] = __builtin_amdgcn_mfma_f32_16x16x32_bf16(af[fm], bfr[fn], acc[fm][fn], 0, 0, 0);
    __syncthreads();
  }
#pragma unroll
  for (int fm = 0; fm < 4; ++fm)
#pragma unroll
    for (int fn = 0; fn < 4; ++fn)
#pragma unroll
      for (int r = 0; r < 4; ++r) {
        int m = bm + wm * 64 + fm * 16 + lg * 4 + r;
        int n = bn + wn * 64 + fn * 16 + lr;
        out[(size_t)m * C_ + n] = acc[fm][fn][r] + bias[n];
      }
}

// ---------------- Flash attention v2: per-wave 32 q-rows, 32x32 MFMA, no LDS ----------------
// swapped QK^T (S^T = K·Q^T) -> lane owns q-row (lane&31); swapped PV (O^T = V^T·P)
// q: [BH][T][D] bf16 (pre-scaled by 0.125); k: [BH][T][D]; vT: [BH][D][T]; yb: [B][T][C] bf16
__global__ void attn_kernel(const ushort* __restrict__ qb,
                            const ushort* __restrict__ kb,
                            const ushort* __restrict__ vT,
                            ushort* __restrict__ yb) {
  const int bh = blockIdx.y;
  const int tid = threadIdx.x, wid = tid >> 6, lane = tid & 63;
  const int l31 = lane & 31, hi = lane >> 5;
  const int wj = blockIdx.x * 4 + wid;           // 0..31
  const int bb = bh >> 4, h = bh & 15;
  const ushort* Qb = qb + (size_t)bh * T_ * D_;
  const ushort* Kb = kb + (size_t)bh * T_ * D_;
  const ushort* Vb = vT + (size_t)bh * D_ * T_;
  const ushort* V0 = Vb + (size_t)(0 * 32 + l31) * T_;
  const ushort* V1 = Vb + (size_t)(1 * 32 + l31) * T_;

  const int i = (blockIdx.z == 0) ? wj : 63 - wj;   // 32-row q-tile index (paired)
  const int qr0 = i * 32;
  const int qrow = qr0 + l31;
  const int ntiles = (i >> 1) + 1;                  // 64-key tiles
  bf16x8 qf[4];
#pragma unroll
  for (int ds = 0; ds < 4; ++ds)
    qf[ds] = *(const bf16x8*)&Qb[(size_t)qrow * D_ + ds * 16 + 8 * hi];
  f32x16 o0 = {}, o1 = {};
  float mrun = -1e30f, lsum = 0.f;

  for (int tx = 0; tx < ntiles; ++tx) {
    const int k0 = tx * 64;
    bf16x8 kf0[4], kf1[4];
#pragma unroll
    for (int ds = 0; ds < 4; ++ds) {
      kf0[ds] = *(const bf16x8*)&Kb[(size_t)(k0 + l31) * D_ + ds * 16 + 8 * hi];
      kf1[ds] = *(const bf16x8*)&Kb[(size_t)(k0 + 32 + l31) * D_ + ds * 16 + 8 * hi];
    }
    bf16x8 vf0[4], vf1[4];
#pragma unroll
    for (int sl = 0; sl < 4; ++sl) {
      vf0[sl] = *(const bf16x8*)&V0[k0 + sl * 16 + 8 * hi];
      vf1[sl] = *(const bf16x8*)&V1[k0 + sl * 16 + 8 * hi];
    }
    // S^T = K Q^T : col = q (lane&31), row = key = (e&3)+8*(e>>2)+4*hi
    f32x16 s0 = {}, s1 = {};
#pragma unroll
    for (int ds = 0; ds < 4; ++ds) {
      s0 = __builtin_amdgcn_mfma_f32_32x32x16_bf16(kf0[ds], qf[ds], s0, 0, 0, 0);
      s1 = __builtin_amdgcn_mfma_f32_32x32x16_bf16(kf1[ds], qf[ds], s1, 0, 0, 0);
    }
    if (tx == ntiles - 1) {
#pragma unroll
      for (int e = 0; e < 16; ++e) {
        int key = k0 + (e & 3) + 8 * (e >> 2) + 4 * hi;
        if (key > qrow)      s0[e] = -1e30f;
        if (key + 32 > qrow) s1[e] = -1e30f;
      }
    }
    // row max: in-lane tree over this lane's 32 values, then cross-half shfl
    float mx;
    {
      float a0 = fmaxf(fmaxf(s0[0], s0[1]), fmaxf(s0[2], s0[3]));
      float a1 = fmaxf(fmaxf(s0[4], s0[5]), fmaxf(s0[6], s0[7]));
      float a2 = fmaxf(fmaxf(s0[8], s0[9]), fmaxf(s0[10], s0[11]));
      float a3 = fmaxf(fmaxf(s0[12], s0[13]), fmaxf(s0[14], s0[15]));
      float b0 = fmaxf(fmaxf(s1[0], s1[1]), fmaxf(s1[2], s1[3]));
      float b1 = fmaxf(fmaxf(s1[4], s1[5]), fmaxf(s1[6], s1[7]));
      float b2 = fmaxf(fmaxf(s1[8], s1[9]), fmaxf(s1[10], s1[11]));
      float b3 = fmaxf(fmaxf(s1[12], s1[13]), fmaxf(s1[14], s1[15]));
      mx = fmaxf(fmaxf(fmaxf(a0, a1), fmaxf(a2, a3)), fmaxf(fmaxf(b0, b1), fmaxf(b2, b3)));
    }
    float pmax = fmaxf(mx, __shfl_xor(mx, 32));    // cross-half (distinct data path, safe)
    // defer-max (T13): rescale only when a row's max grew by > 8
    if (!__all(pmax - mrun <= 8.f)) {
      float nm = fmaxf(mrun, pmax);
      float sc = __expf(mrun - nm);
#pragma unroll
      for (int e = 0; e < 16; ++e) { o0[e] *= sc; o1[e] *= sc; }
      lsum *= sc;
      mrun = nm;
    }
    float ls0 = 0.f, ls1 = 0.f, ls2 = 0.f, ls3 = 0.f;
#pragma unroll
    for (int e = 0; e < 4; ++e) {
      s0[e]      = __expf(s0[e]      - mrun); ls0 += s0[e];
      s0[e + 4]  = __expf(s0[e + 4]  - mrun); ls1 += s0[e + 4];
      s0[e + 8]  = __expf(s0[e + 8]  - mrun); ls2 += s0[e + 8];
      s0[e + 12] = __expf(s0[e + 12] - mrun); ls3 += s0[e + 12];
    }
#pragma unroll
    for (int e = 0; e < 4; ++e) {
      s1[e]      = __expf(s1[e]      - mrun); ls0 += s1[e];
      s1[e + 4]  = __expf(s1[e + 4]  - mrun); ls1 += s1[e + 4];
      s1[e + 8]  = __expf(s1[e + 8]  - mrun); ls2 += s1[e + 8];
      s1[e + 12] = __expf(s1[e + 12] - mrun); ls3 += s1[e + 12];
    }
    lsum += (ls0 + ls1) + (ls2 + ls3);
    // build P fragments (B-operand): lane needs P[key = 16*sl + 8*hi + j][q]
    // v_permlane32_swap_b32 VDST, SRC0: VDST.upper32 <-> SRC0.lower32.
    // VDST = earlier-keys word, SRC0 = later-keys word:
    //   u(new) = [u.lo | w.lo] -> word0 ; w(new) = [u.hi | w.hi] -> word2
    bf16x8 pb[4];
#pragma unroll
    for (int half = 0; half < 2; ++half) {
      const f32x16& sv = half == 0 ? s0 : s1;
#pragma unroll
      for (int ss = 0; ss < 2; ++ss) {
        unsigned u = cvtpk_bf16(sv[ss * 8 + 0], sv[ss * 8 + 1]);
        unsigned v = cvtpk_bf16(sv[ss * 8 + 2], sv[ss * 8 + 3]);
        unsigned w = cvtpk_bf16(sv[ss * 8 + 4], sv[ss * 8 + 5]);
        unsigned z = cvtpk_bf16(sv[ss * 8 + 6], sv[ss * 8 + 7]);
        asm("v_permlane32_swap_b32 %0, %1" : "+v"(u), "+v"(w));
        asm("v_permlane32_swap_b32 %0, %1" : "+v"(v), "+v"(z));
        union { unsigned w4[4]; bf16x8 f; } pk;
        pk.w4[0] = u; pk.w4[1] = v; pk.w4[2] = w; pk.w4[3] = z;
        pb[half * 2 + ss] = pk.f;
      }
    }
    // O^T += V^T P : col = q (lane&31), row = d
#pragma unroll
    for (int sl = 0; sl < 4; ++sl) {
      o0 = __builtin_amdgcn_mfma_f32_32x32x16_bf16(vf0[sl], pb[sl], o0, 0, 0, 0);
      o1 = __builtin_amdgcn_mfma_f32_32x32x16_bf16(vf1[sl], pb[sl], o1, 0, 0, 0);
    }
  }
  float lt = lsum + __shfl_xor(lsum, 32);
  float linv = 1.f / lt;
  ushort* yrow = yb + ((size_t)(bb * T_ + qrow)) * C_ + h * D_;
#pragma unroll
  for (int rg = 0; rg < 4; ++rg) {
    ushort4 w0, w1;
    w0.x = f2bf(o0[rg * 4 + 0] * linv); w0.y = f2bf(o0[rg * 4 + 1] * linv);
    w0.z = f2bf(o0[rg * 4 + 2] * linv); w0.w = f2bf(o0[rg * 4 + 3] * linv);
    w1.x = f2bf(o1[rg * 4 + 0] * linv); w1.y = f2bf(o1[rg * 4 + 1] * linv);
    w1.z = f2bf(o1[rg * 4 + 2] * linv); w1.w = f2bf(o1[rg * 4 + 3] * linv);
    *(ushort4*)&yrow[8 * rg + 4 * hi]      = w0;
    *(ushort4*)&yrow[32 + 8 * rg + 4 * hi] = w1;
  }
}

// ---------------------------------------------------------------------------
extern "C" void kernel_launch(void* const* d_in, const int* in_sizes, int n_in,
                              void* d_out, int out_size, void* d_ws, size_t ws_size,
                              hipStream_t stream) {
  const float* x      = (const float*)d_in[0];
  const float* w_qkv  = (const float*)d_in[1];
  const float* b_qkv  = (const float*)d_in[2];
  const float* w_proj = (const float*)d_in[3];
  const float* b_proj = (const float*)d_in[4];
  float* out = (float*)d_out;

  char* ws = (char*)d_ws;
  const size_t MB = 1024 * 1024;
  ushort* xb     = (ushort*)(ws);                 // 16 MB  [8192][1024]
  ushort* wqkvT  = (ushort*)(ws + 16 * MB);       // 6  MB  [3072][1024]
  ushort* wprojT = (ushort*)(ws + 22 * MB);       // 2  MB  [1024][1024]
  ushort* qbuf   = (ushort*)(ws + 24 * MB);       // 16 MB  [64][2048][64]
  ushort* kbuf   = (ushort*)(ws + 40 * MB);       // 16 MB  [64][2048][64]
  ushort* vTbuf  = (ushort*)(ws + 56 * MB);       // 16 MB  [64][64][2048]
  ushort* ybuf   = (ushort*)(ws + 72 * MB);       // 16 MB  [8192][1024]

  cvt_bf16_kernel<<<2048, 256, 0, stream>>>(x, xb, M_ * C_ / 4);
  transpose_cvt_kernel<<<dim3(N3_ / 64, C_ / 64), 256, 0, stream>>>(w_qkv, wqkvT, C_, N3_);
  transpose_cvt_kernel<<<dim3(C_ / 64, C_ / 64), 256, 0, stream>>>(w_proj, wprojT, C_, C_);
  gemm_qkv_kernel<<<dim3(N3_ / 128, M_ / 128), 256, 0, stream>>>(xb, wqkvT, b_qkv, qbuf, kbuf, vTbuf);
  attn_kernel<<<dim3(8, B_ * H_, 2), 256, 0, stream>>>(qbuf, kbuf, vTbuf, ybuf);
  gemm_proj_kernel<<<dim3(C_ / 128, M_ / 128), 256, 0, stream>>>(ybuf, wprojT, b_proj, out);
}

// Round 9
// 330.257 us; speedup vs baseline: 1.0982x; 1.0982x over previous
//
#include <hip/hip_runtime.h>
#include <hip/hip_bf16.h>

#define B_ 4
#define T_ 2048
#define C_ 1024
#define H_ 16
#define D_ 64
#define M_ (B_ * T_)   // 8192
#define N3_ (3 * C_)   // 3072

typedef __attribute__((ext_vector_type(4))) float f32x4;
typedef __attribute__((ext_vector_type(16))) float f32x16;
typedef __attribute__((ext_vector_type(8))) short bf16x8;

__device__ __forceinline__ ushort f2bf(float f) {
  union { float f; unsigned u; } v; v.f = f;
  unsigned r = v.u + 0x7fffu + ((v.u >> 16) & 1u);
  return (ushort)(r >> 16);
}

__device__ __forceinline__ void gload_lds16(const ushort* g, ushort* l) {
  __builtin_amdgcn_global_load_lds((const __attribute__((address_space(1))) void*)g,
                                   (__attribute__((address_space(3))) void*)l, 16, 0, 0);
}

__device__ __forceinline__ unsigned cvtpk_bf16(float lo, float hi) {
  unsigned r;
  asm("v_cvt_pk_bf16_f32 %0, %1, %2" : "=v"(r) : "v"(lo), "v"(hi));
  return r;
}

__device__ __forceinline__ float exp2fast(float x) {
  return __builtin_amdgcn_exp2f(x);   // v_exp_f32: 2^x
}

// ---------------- cast f32 -> bf16 (vectorized) ----------------
__global__ void cvt_bf16_kernel(const float* __restrict__ in, ushort* __restrict__ out, int n4) {
  int i = blockIdx.x * blockDim.x + threadIdx.x;
  int stride = gridDim.x * blockDim.x;
  for (; i < n4; i += stride) {
    float4 v = reinterpret_cast<const float4*>(in)[i];
    ushort4 o;
    o.x = f2bf(v.x); o.y = f2bf(v.y); o.z = f2bf(v.z); o.w = f2bf(v.w);
    reinterpret_cast<ushort4*>(out)[i] = o;
  }
}

// ------------- transpose + cast: in[K][N] f32 -> out[N][K] bf16 -------------
__global__ __launch_bounds__(256) void transpose_cvt_kernel(const float* __restrict__ in,
                                                            ushort* __restrict__ out,
                                                            int K, int N) {
  __shared__ float tile[64][65];
  int k0 = blockIdx.y * 64, n0 = blockIdx.x * 64;
  int t = threadIdx.x;
  int rr = t >> 6, cc = t & 63;
#pragma unroll
  for (int i = 0; i < 16; ++i) {
    int r = i * 4 + rr;
    tile[r][cc] = in[(size_t)(k0 + r) * N + n0 + cc];
  }
  __syncthreads();
#pragma unroll
  for (int i = 0; i < 16; ++i) {
    int r = i * 4 + rr;
    out[(size_t)(n0 + r) * K + k0 + cc] = f2bf(tile[cc][r]);
  }
}

// ---------------- QKV GEMM (m97 structure): qkv = x @ w_qkv + b -> q/k/vT ----------------
// q gets pre-scaled by (1/sqrt(D)) * log2(e) here (folded softmax+exp2 scale).
#define QSCALE 0.1803368801111244f
__global__ __launch_bounds__(256) void gemm_qkv_kernel(const ushort* __restrict__ A,
                                                       const ushort* __restrict__ Bt,
                                                       const float* __restrict__ bias,
                                                       ushort* __restrict__ qb,
                                                       ushort* __restrict__ kb,
                                                       ushort* __restrict__ vT) {
  __shared__ __align__(16) ushort As[128 * 32];
  __shared__ __align__(16) ushort Bs[128 * 32];
  const int tid = threadIdx.x;
  const int wid = tid >> 6, lane = tid & 63;
  const int wm = wid >> 1, wn = wid & 1;
  const int lr = lane & 15, lg = lane >> 4;
  const int bm = blockIdx.y * 128, bn = blockIdx.x * 128;
  const int srow = wid * 32 + (lane >> 2);
  const int scol = (lane & 3) * 8;
  ushort* lA = &As[wid * 32 * 32];
  ushort* lB = &Bs[wid * 32 * 32];
  const ushort* gA0 = A  + (size_t)(bm + srow) * 1024 + scol;
  const ushort* gB0 = Bt + (size_t)(bn + srow) * 1024 + scol;
  f32x4 acc[4][4] = {};
  for (int k0 = 0; k0 < 1024; k0 += 32) {
    gload_lds16(gA0 + k0, lA);
    gload_lds16(gA0 + k0 + 16 * 1024, lA + 16 * 32);
    gload_lds16(gB0 + k0, lB);
    gload_lds16(gB0 + k0 + 16 * 1024, lB + 16 * 32);
    __syncthreads();
    bf16x8 af[4], bfr[4];
#pragma unroll
    for (int f = 0; f < 4; ++f) {
      af[f]  = *(const bf16x8*)&As[(wm * 64 + f * 16 + lr) * 32 + lg * 8];
      bfr[f] = *(const bf16x8*)&Bs[(wn * 64 + f * 16 + lr) * 32 + lg * 8];
    }
#pragma unroll
    for (int fm = 0; fm < 4; ++fm)
#pragma unroll
      for (int fn = 0; fn < 4; ++fn)
        acc[fm][fn] = __builtin_amdgcn_mfma_f32_16x16x32_bf16(af[fm], bfr[fn], acc[fm][fn], 0, 0, 0);
    __syncthreads();
  }
#pragma unroll
  for (int fm = 0; fm < 4; ++fm)
#pragma unroll
    for (int fn = 0; fn < 4; ++fn) {
      int m0 = bm + wm * 64 + fm * 16 + lg * 4;
      int n  = bn + wn * 64 + fn * 16 + lr;
      float b = bias[n];
      int part = n >> 10, cch = n & 1023;
      int h = cch >> 6, d = cch & 63;
      int bb = m0 >> 11, t = m0 & 2047;
      size_t bh = (size_t)bb * H_ + h;
      if (part == 2) {
        ushort4 pv;
        pv.x = f2bf(acc[fm][fn][0] + b);
        pv.y = f2bf(acc[fm][fn][1] + b);
        pv.z = f2bf(acc[fm][fn][2] + b);
        pv.w = f2bf(acc[fm][fn][3] + b);
        *(ushort4*)&vT[(bh * D_ + d) * T_ + t] = pv;
      } else if (part == 0) {
#pragma unroll
        for (int r = 0; r < 4; ++r)
          qb[(bh * T_ + t + r) * D_ + d] = f2bf((acc[fm][fn][r] + b) * QSCALE);
      } else {
#pragma unroll
        for (int r = 0; r < 4; ++r)
          kb[(bh * T_ + t + r) * D_ + d] = f2bf(acc[fm][fn][r] + b);
      }
    }
}

// ---------------- Proj GEMM (m97 structure): out = y @ w_proj + b (f32 out) ----------------
__global__ __launch_bounds__(256) void gemm_proj_kernel(const ushort* __restrict__ A,
                                                        const ushort* __restrict__ Bt,
                                                        const float* __restrict__ bias,
                                                        float* __restrict__ out) {
  __shared__ __align__(16) ushort As[128 * 32];
  __shared__ __align__(16) ushort Bs[128 * 32];
  const int tid = threadIdx.x;
  const int wid = tid >> 6, lane = tid & 63;
  const int wm = wid >> 1, wn = wid & 1;
  const int lr = lane & 15, lg = lane >> 4;
  const int bm = blockIdx.y * 128, bn = blockIdx.x * 128;
  const int srow = wid * 32 + (lane >> 2);
  const int scol = (lane & 3) * 8;
  ushort* lA = &As[wid * 32 * 32];
  ushort* lB = &Bs[wid * 32 * 32];
  const ushort* gA0 = A  + (size_t)(bm + srow) * 1024 + scol;
  const ushort* gB0 = Bt + (size_t)(bn + srow) * 1024 + scol;
  f32x4 acc[4][4] = {};
  for (int k0 = 0; k0 < 1024; k0 += 32) {
    gload_lds16(gA0 + k0, lA);
    gload_lds16(gA0 + k0 + 16 * 1024, lA + 16 * 32);
    gload_lds16(gB0 + k0, lB);
    gload_lds16(gB0 + k0 + 16 * 1024, lB + 16 * 32);
    __syncthreads();
    bf16x8 af[4], bfr[4];
#pragma unroll
    for (int f = 0; f < 4; ++f) {
      af[f]  = *(const bf16x8*)&As[(wm * 64 + f * 16 + lr) * 32 + lg * 8];
      bfr[f] = *(const bf16x8*)&Bs[(wn * 64 + f * 16 + lr) * 32 + lg * 8];
    }
#pragma unroll
    for (int fm = 0; fm < 4; ++fm)
#pragma unroll
      for (int fn = 0; fn < 4; ++fn)
        acc[fm][fn] = __builtin_amdgcn_mfma_f32_16x16x32_bf16(af[fm], bfr[fn], acc[fm][fn], 0, 0, 0);
    __syncthreads();
  }
#pragma unroll
  for (int fm = 0; fm < 4; ++fm)
#pragma unroll
    for (int fn = 0; fn < 4; ++fn)
#pragma unroll
      for (int r = 0; r < 4; ++r) {
        int m = bm + wm * 64 + fm * 16 + lg * 4 + r;
        int n = bn + wn * 64 + fn * 16 + lr;
        out[(size_t)m * C_ + n] = acc[fm][fn][r] + bias[n];
      }
}

// ---------------- Flash attention v3: per-wave 32 q-rows, 32x32 MFMA, no LDS ----------------
// Within-wave causal pairing (i then 63-i): uniform 33 tiles/wave.
// K prefetched one tile ahead (A/B reg double-buffer); V loaded at compute-top.
// q: [BH][T][D] bf16 (pre-scaled by 0.125*log2e); k: [BH][T][D]; vT: [BH][D][T]; yb: [B][T][C] bf16
__global__ __launch_bounds__(256, 2) void attn_kernel(const ushort* __restrict__ qb,
                                                      const ushort* __restrict__ kb,
                                                      const ushort* __restrict__ vT,
                                                      ushort* __restrict__ yb) {
  const int bh = blockIdx.x;                      // head id -> id%8 = bh%8 (XCD co-location)
  const int tid = threadIdx.x, wid = tid >> 6, lane = tid & 63;
  const int l31 = lane & 31, hi = lane >> 5;
  const int wj = blockIdx.y * 4 + wid;            // 0..31 pair index
  const int bb = bh >> 4, h = bh & 15;
  const ushort* Qb = qb + (size_t)bh * T_ * D_;
  const ushort* Kb = kb + (size_t)bh * T_ * D_;
  const ushort* Vb = vT + (size_t)bh * D_ * T_;
  const ushort* V0 = Vb + (size_t)(l31) * T_;
  const ushort* V1 = Vb + (size_t)(32 + l31) * T_;

#define LOADK(TX, KF0, KF1)                                                        \
  do {                                                                             \
    const int kk_ = (TX) * 64;                                                     \
    _Pragma("unroll") for (int ds_ = 0; ds_ < 4; ++ds_) {                          \
      KF0[ds_] = *(const bf16x8*)&Kb[(size_t)(kk_ + l31) * D_ + ds_ * 16 + 8 * hi];      \
      KF1[ds_] = *(const bf16x8*)&Kb[(size_t)(kk_ + 32 + l31) * D_ + ds_ * 16 + 8 * hi]; \
    }                                                                              \
  } while (0)

#define COMPUTE(TX, KF0, KF1)                                                      \
  do {                                                                             \
    const int k0_ = (TX) * 64;                                                     \
    bf16x8 vf0_[4], vf1_[4];                                                       \
    _Pragma("unroll") for (int sl_ = 0; sl_ < 4; ++sl_) {                          \
      vf0_[sl_] = *(const bf16x8*)&V0[k0_ + sl_ * 16 + 8 * hi];                    \
      vf1_[sl_] = *(const bf16x8*)&V1[k0_ + sl_ * 16 + 8 * hi];                    \
    }                                                                              \
    f32x16 s0 = {}, s1 = {};                                                       \
    _Pragma("unroll") for (int ds_ = 0; ds_ < 4; ++ds_) {                          \
      s0 = __builtin_amdgcn_mfma_f32_32x32x16_bf16(KF0[ds_], qf[ds_], s0, 0, 0, 0);\
      s1 = __builtin_amdgcn_mfma_f32_32x32x16_bf16(KF1[ds_], qf[ds_], s1, 0, 0, 0);\
    }                                                                              \
    if ((TX) == ntiles - 1) {                                                      \
      _Pragma("unroll") for (int e = 0; e < 16; ++e) {                             \
        int key = k0_ + (e & 3) + 8 * (e >> 2) + 4 * hi;                           \
        if (key > qrow)      s0[e] = -1e30f;                                       \
        if (key + 32 > qrow) s1[e] = -1e30f;                                       \
      }                                                                            \
    }                                                                              \
    float mx;                                                                      \
    {                                                                              \
      float a0 = fmaxf(fmaxf(s0[0], s0[1]), fmaxf(s0[2], s0[3]));                  \
      float a1 = fmaxf(fmaxf(s0[4], s0[5]), fmaxf(s0[6], s0[7]));                  \
      float a2 = fmaxf(fmaxf(s0[8], s0[9]), fmaxf(s0[10], s0[11]));                \
      float a3 = fmaxf(fmaxf(s0[12], s0[13]), fmaxf(s0[14], s0[15]));              \
      float b0 = fmaxf(fmaxf(s1[0], s1[1]), fmaxf(s1[2], s1[3]));                  \
      float b1 = fmaxf(fmaxf(s1[4], s1[5]), fmaxf(s1[6], s1[7]));                  \
      float b2 = fmaxf(fmaxf(s1[8], s1[9]), fmaxf(s1[10], s1[11]));                \
      float b3 = fmaxf(fmaxf(s1[12], s1[13]), fmaxf(s1[14], s1[15]));              \
      mx = fmaxf(fmaxf(fmaxf(a0, a1), fmaxf(a2, a3)),                              \
                 fmaxf(fmaxf(b0, b1), fmaxf(b2, b3)));                             \
    }                                                                              \
    float pmax = fmaxf(mx, __shfl_xor(mx, 32));                                    \
    if (!__all(pmax - mrun <= 8.f)) {                                              \
      float nm = fmaxf(mrun, pmax);                                                \
      float sc = exp2fast(mrun - nm);                                              \
      _Pragma("unroll") for (int e = 0; e < 16; ++e) { o0[e] *= sc; o1[e] *= sc; } \
      lsum *= sc;                                                                  \
      mrun = nm;                                                                   \
    }                                                                              \
    float ls_ = 0.f;                                                               \
    _Pragma("unroll") for (int e = 0; e < 16; ++e) {                               \
      s0[e] = exp2fast(s0[e] - mrun); ls_ += s0[e];                                \
      s1[e] = exp2fast(s1[e] - mrun); ls_ += s1[e];                                \
    }                                                                              \
    lsum += ls_;                                                                   \
    bf16x8 pb[4];                                                                  \
    _Pragma("unroll") for (int half = 0; half < 2; ++half) {                       \
      const f32x16& sv = half == 0 ? s0 : s1;                                      \
      _Pragma("unroll") for (int ss = 0; ss < 2; ++ss) {                           \
        unsigned u = cvtpk_bf16(sv[ss * 8 + 0], sv[ss * 8 + 1]);                   \
        unsigned v = cvtpk_bf16(sv[ss * 8 + 2], sv[ss * 8 + 3]);                   \
        unsigned w = cvtpk_bf16(sv[ss * 8 + 4], sv[ss * 8 + 5]);                   \
        unsigned z = cvtpk_bf16(sv[ss * 8 + 6], sv[ss * 8 + 7]);                   \
        asm("v_permlane32_swap_b32 %0, %1" : "+v"(u), "+v"(w));                    \
        asm("v_permlane32_swap_b32 %0, %1" : "+v"(v), "+v"(z));                    \
        union { unsigned w4[4]; bf16x8 f; } pk;                                    \
        pk.w4[0] = u; pk.w4[1] = v; pk.w4[2] = w; pk.w4[3] = z;                    \
        pb[half * 2 + ss] = pk.f;                                                  \
      }                                                                            \
    }                                                                              \
    _Pragma("unroll") for (int sl_ = 0; sl_ < 4; ++sl_) {                          \
      o0 = __builtin_amdgcn_mfma_f32_32x32x16_bf16(vf0_[sl_], pb[sl_], o0, 0, 0, 0);\
      o1 = __builtin_amdgcn_mfma_f32_32x32x16_bf16(vf1_[sl_], pb[sl_], o1, 0, 0, 0);\
    }                                                                              \
  } while (0)

  for (int pass = 0; pass < 2; ++pass) {
    const int i = (pass == 0) ? wj : 63 - wj;     // q-tile index
    const int qrow = i * 32 + l31;
    const int ntiles = (i >> 1) + 1;              // 64-key tiles
    bf16x8 qf[4];
#pragma unroll
    for (int ds = 0; ds < 4; ++ds)
      qf[ds] = *(const bf16x8*)&Qb[(size_t)qrow * D_ + ds * 16 + 8 * hi];
    f32x16 o0 = {}, o1 = {};
    float mrun = -1e30f, lsum = 0.f;

    bf16x8 kA0[4], kA1[4], kB0[4], kB1[4];
    LOADK(0, kA0, kA1);
    int tx = 0;
    while (tx < ntiles) {
      if (tx + 1 < ntiles) LOADK(tx + 1, kB0, kB1);
      COMPUTE(tx, kA0, kA1);
      ++tx;
      if (tx < ntiles) {
        if (tx + 1 < ntiles) LOADK(tx + 1, kA0, kA1);
        COMPUTE(tx, kB0, kB1);
        ++tx;
      }
    }

    float lt = lsum + __shfl_xor(lsum, 32);
    float linv = 1.f / lt;
    ushort* yrow = yb + ((size_t)(bb * T_ + qrow)) * C_ + h * D_;
#pragma unroll
    for (int rg = 0; rg < 4; ++rg) {
      ushort4 w0, w1;
      w0.x = f2bf(o0[rg * 4 + 0] * linv); w0.y = f2bf(o0[rg * 4 + 1] * linv);
      w0.z = f2bf(o0[rg * 4 + 2] * linv); w0.w = f2bf(o0[rg * 4 + 3] * linv);
      w1.x = f2bf(o1[rg * 4 + 0] * linv); w1.y = f2bf(o1[rg * 4 + 1] * linv);
      w1.z = f2bf(o1[rg * 4 + 2] * linv); w1.w = f2bf(o1[rg * 4 + 3] * linv);
      *(ushort4*)&yrow[8 * rg + 4 * hi]      = w0;
      *(ushort4*)&yrow[32 + 8 * rg + 4 * hi] = w1;
    }
  }
#undef LOADK
#undef COMPUTE
}

// ---------------------------------------------------------------------------
extern "C" void kernel_launch(void* const* d_in, const int* in_sizes, int n_in,
                              void* d_out, int out_size, void* d_ws, size_t ws_size,
                              hipStream_t stream) {
  const float* x      = (const float*)d_in[0];
  const float* w_qkv  = (const float*)d_in[1];
  const float* b_qkv  = (const float*)d_in[2];
  const float* w_proj = (const float*)d_in[3];
  const float* b_proj = (const float*)d_in[4];
  float* out = (float*)d_out;

  char* ws = (char*)d_ws;
  const size_t MB = 1024 * 1024;
  ushort* xb     = (ushort*)(ws);                 // 16 MB  [8192][1024]
  ushort* wqkvT  = (ushort*)(ws + 16 * MB);       // 6  MB  [3072][1024]
  ushort* wprojT = (ushort*)(ws + 22 * MB);       // 2  MB  [1024][1024]
  ushort* qbuf   = (ushort*)(ws + 24 * MB);       // 16 MB  [64][2048][64]
  ushort* kbuf   = (ushort*)(ws + 40 * MB);       // 16 MB  [64][2048][64]
  ushort* vTbuf  = (ushort*)(ws + 56 * MB);       // 16 MB  [64][64][2048]
  ushort* ybuf   = (ushort*)(ws + 72 * MB);       // 16 MB  [8192][1024]

  cvt_bf16_kernel<<<2048, 256, 0, stream>>>(x, xb, M_ * C_ / 4);
  transpose_cvt_kernel<<<dim3(N3_ / 64, C_ / 64), 256, 0, stream>>>(w_qkv, wqkvT, C_, N3_);
  transpose_cvt_kernel<<<dim3(C_ / 64, C_ / 64), 256, 0, stream>>>(w_proj, wprojT, C_, C_);
  gemm_qkv_kernel<<<dim3(N3_ / 128, M_ / 128), 256, 0, stream>>>(xb, wqkvT, b_qkv, qbuf, kbuf, vTbuf);
  attn_kernel<<<dim3(B_ * H_, 8), 256, 0, stream>>>(qbuf, kbuf, vTbuf, ybuf);
  gemm_proj_kernel<<<dim3(C_ / 128, M_ / 128), 256, 0, stream>>>(ybuf, wprojT, b_proj, out);
}